// Round 3
// baseline (284.604 us; speedup 1.0000x reference)
//
#include <hip/hip_runtime.h>
#include <cstdint>
#include <cstddef>

// GraphSAGE 2-layer fused pipeline, MI355X.
// Identity: segment_mean(x[src]) @ W == segment_mean((x@W)[src]) -> GEMM before gather.
// R22 == R21 resubmitted verbatim (R21 bench failed with GPUAcquisitionTimeout;
// no counters were produced, theory untested).
// R21: k_agg1 was VALU-issue-bound (VALUBusy 64%, gathers in flight only ~5% of
// wall; ~300 VALU inst/node dominated by bf16 unpack + 4 f32 divides + bf16
// repack). Changes:
//   (a) xl / hroot / hbuf stored f32 (not bf16): float4 gathers, zero unpack
//       bit-ops, float4 store (no RNE pack). Gather traffic 2x (410MB) but
//       LLC-resident (xl=25.6MB) and memory duty was ~5% -> free.
//   (b) one reciprocal + 4 FMA per node instead of 4 full f32 divides.
//   (c) dual-node interleave (A,B) per wave iteration; bucket rows loaded
//       UNCONDITIONALLY (rows fully written by k_bucketB; lane<m mask applied
//       at use) -> cnt->bucket dependent chain gone; next-pair cnt+bucket
//       prefetched one iteration ahead.
//   (d) k_scanB eliminated: scanA lane0 assigns bin base via global atomicAdd
//       cursor (part ranges need only be disjoint, not ordered); bucketB uses
//       e1 = binbase[b] + tot[b]. Cursor zeroed in k_hist wprep tail block.

#define CAP 64
#define BINSZ 128        // nodes per bin (dst >> 7)
#define CH 4096          // edges per chunk block

typedef __attribute__((ext_vector_type(8))) short bf16x8v;
typedef __attribute__((ext_vector_type(4))) float f32x4v;

__device__ __forceinline__ float bf2f(unsigned short u) {
  return __uint_as_float(((unsigned int)u) << 16);
}
__device__ __forceinline__ unsigned short f2bf(float f) {
  unsigned int x = __float_as_uint(f);
  unsigned int r = (x + 0x7fffu + ((x >> 16) & 1u)) >> 16;  // RNE
  return (unsigned short)r;
}

// ---------------- pass 1: per-chunk histogram over dst bins + (tail blocks) W-swizzle ----------------
__global__ __launch_bounds__(256) void k_hist(const int* __restrict__ ei,
                                              int* __restrict__ hist,
                                              const float* __restrict__ W1l,
                                              const float* __restrict__ W1r,
                                              unsigned short* __restrict__ wswz,
                                              int* __restrict__ cursor,
                                              int E, int NB, int NCH) {
  const int t = threadIdx.x;
  if (blockIdx.x >= (unsigned)NCH) {
    if (blockIdx.x == (unsigned)NCH && t == 0) *cursor = 0;  // scanA base cursor
    // wprep tail: 64 blocks cover 16384 swizzled bf16 weights
    int idx = (blockIdx.x - NCH) * 256 + t;
    int j = idx & 7;
    int lane = (idx >> 3) & 63;
    int c = (idx >> 9) & 7;
    int t4 = idx >> 12;
    int kk = t4 * 32 + (lane >> 4) * 8 + j;
    int nn = c * 16 + (lane & 15);
    float v = (nn < 64) ? W1l[kk * 64 + nn] : W1r[kk * 64 + (nn - 64)];
    wswz[idx] = f2bf(v);
    return;
  }
  __shared__ int lcnt[1024];
  const int c = blockIdx.x;
  for (int i = t; i < NB; i += 256) lcnt[i] = 0;
  __syncthreads();
  const int base = c * CH;
  const int end = min(base + CH, E);
  for (int e = base + t; e < end; e += 256) {
    int d = ei[E + e];
    atomicAdd(&lcnt[d >> 7], 1);  // LDS int atomic (native, fast)
  }
  __syncthreads();
  for (int i = t; i < NB; i += 256) hist[(size_t)i * NCH + c] = lcnt[i];
}

// ---------------- merged: [head blocks] per-bin scan over chunks  |  [tail blocks] layer-1 GEMM ----------------
// scanA: 1 wave/bin exclusive scan of hist rows -> tot + atomic binbase.
// gemm1: [xl|hroot] = x @ [W1l|W1r] (+b1), f32 outputs.
__global__ __launch_bounds__(256) void k_scan_gemm(
    int* __restrict__ hist, int* __restrict__ tot, int* __restrict__ binbase,
    int* __restrict__ cursor, int NB, int NCH, int nScan,
    const float* __restrict__ x, const unsigned short* __restrict__ wswz,
    const float* __restrict__ b1, float* __restrict__ xl,
    float* __restrict__ hroot, int Nn) {
  if (blockIdx.x < (unsigned)nScan) {
    const int lane = threadIdx.x & 63;
    const int bin = blockIdx.x * 4 + (threadIdx.x >> 6);
    if (bin >= NB) return;
    int* h = hist + (size_t)bin * NCH;
    int carry = 0;
    for (int base = 0; base < NCH; base += 64) {
      int i = base + lane;
      int v = (i < NCH) ? h[i] : 0;
      int incl = v;
      #pragma unroll
      for (int d = 1; d < 64; d <<= 1) {
        int t = __shfl_up(incl, d, 64);
        if (lane >= d) incl += t;
      }
      if (i < NCH) h[i] = carry + incl - v;  // exclusive prefix within bin
      carry += __shfl(incl, 63, 64);
    }
    if (lane == 0) {
      tot[bin] = carry;
      binbase[bin] = atomicAdd(cursor, carry);  // disjoint range, order-free
    }
    return;
  }
  // ---- gemm1 body ----
  __shared__ unsigned short Bsw[16384];  // 32 KB
  const int t = threadIdx.x;
  const int bid = blockIdx.x - nScan;
  {
    const uint4* src = (const uint4*)wswz;
    uint4* dst = (uint4*)Bsw;
    #pragma unroll
    for (int i = 0; i < 8; ++i) dst[t + i * 256] = src[t + i * 256];
  }
  __syncthreads();

  const int lane = t & 63;
  const int wid = t >> 6;
  const int quad = lane >> 4;
  const int m = lane & 15;
  const int rowA = bid * 64 + wid * 16 + m;
  const float* xrow = x + (size_t)min(rowA, Nn - 1) * 128;

  f32x4v acc[8];
  #pragma unroll
  for (int c = 0; c < 8; ++c) acc[c] = (f32x4v){0.f, 0.f, 0.f, 0.f};

  #pragma unroll
  for (int t4 = 0; t4 < 4; ++t4) {
    const int koff = t4 * 32 + quad * 8;
    float4 a0 = *(const float4*)(xrow + koff);
    float4 a1 = *(const float4*)(xrow + koff + 4);
    bf16x8v af;
    af[0] = (short)f2bf(a0.x); af[1] = (short)f2bf(a0.y);
    af[2] = (short)f2bf(a0.z); af[3] = (short)f2bf(a0.w);
    af[4] = (short)f2bf(a1.x); af[5] = (short)f2bf(a1.y);
    af[6] = (short)f2bf(a1.z); af[7] = (short)f2bf(a1.w);
    #pragma unroll
    for (int c = 0; c < 8; ++c) {
      const bf16x8v bf_ = *(const bf16x8v*)&Bsw[(((t4 * 8 + c) * 64 + lane)) << 3];
      acc[c] = __builtin_amdgcn_mfma_f32_16x16x32_bf16(af, bf_, acc[c], 0, 0, 0);
    }
  }

  const int rbase = bid * 64 + wid * 16 + quad * 4;
  #pragma unroll
  for (int c = 0; c < 8; ++c) {
    const int col = c * 16 + m;
    #pragma unroll
    for (int i = 0; i < 4; ++i) {
      const int r = rbase + i;
      if (r < Nn) {
        if (c < 4) xl[(size_t)r * 64 + col] = acc[c][i];
        else       hroot[(size_t)r * 64 + (col - 64)] = acc[c][i] + b1[col - 64];
      }
    }
  }
}

// ---------------- pass 3: scatter edges to bin-sorted array (LDS cursors only) ----------------
__global__ __launch_bounds__(256) void k_scat(const int* __restrict__ ei,
                                              const int* __restrict__ hist,
                                              const int* __restrict__ binbase,
                                              unsigned int* __restrict__ part,
                                              int E, int NB, int NCH) {
  __shared__ int lcur[1024];
  const int c = blockIdx.x, t = threadIdx.x;
  for (int i = t; i < NB; i += 256)
    lcur[i] = hist[(size_t)i * NCH + c] + binbase[i];
  __syncthreads();
  const int base = c * CH;
  const int end = min(base + CH, E);
  for (int e = base + t; e < end; e += 256) {
    int s = ei[e];        // src < 2^17
    int d = ei[E + e];    // dst
    int bin = d >> 7;
    int pos = atomicAdd(&lcur[bin], 1);  // LDS int atomic; positions exact
    part[pos] = (unsigned)s | ((unsigned)(d & 127) << 17);
  }
}

// ---------------- pass 4: per-bin bucket build in LDS, coalesced writeout ----------------
__global__ __launch_bounds__(256) void k_bucketB(const int* __restrict__ binbase,
                                                 const int* __restrict__ tot,
                                                 const unsigned int* __restrict__ part,
                                                 int* __restrict__ cnt,
                                                 int* __restrict__ bucket) {
  __shared__ int lbkt[BINSZ * CAP];  // 32 KB
  __shared__ int ldeg[BINSZ];
  const int b = blockIdx.x, t = threadIdx.x;
  if (t < BINSZ) ldeg[t] = 0;
  __syncthreads();
  const int e0 = binbase[b], e1 = e0 + tot[b];
  for (int i = e0 + t; i < e1; i += 256) {
    unsigned rec = part[i];
    int loc = rec >> 17;
    int p = atomicAdd(&ldeg[loc], 1);
    if (p < CAP) lbkt[loc * CAP + p] = (int)(rec & 0x1FFFFu);
  }
  __syncthreads();
  if (t < BINSZ) cnt[b * BINSZ + t] = ldeg[t];
  const int4* s4 = (const int4*)lbkt;
  int4* d4 = (int4*)(bucket + (size_t)b * BINSZ * CAP);
  #pragma unroll 2
  for (int i = t; i < BINSZ * CAP / 4; i += 256) d4[i] = s4[i];
}

// ---------------- layer-1 aggregate: h = relu(mean_nb(xl) + hroot), f32 path ----------------
// Wave per node-pair (A = n, B = n + nw), outer stride 2*nw. lane q=lane&15
// covers float4 {4q..4q+3}; g=lane>>4 picks edge subgroup. All f32: no unpack.
#define GLOAD4(sidx, i, u0, u1, u2, u3)                          \
  {                                                              \
    int r0_ = __shfl(sidx, (i) + g, 64);                         \
    int r1_ = __shfl(sidx, (i) + 4 + g, 64);                     \
    int r2_ = __shfl(sidx, (i) + 8 + g, 64);                     \
    int r3_ = __shfl(sidx, (i) + 12 + g, 64);                    \
    u0 = *(const float4*)(xlf + (size_t)r0_ * 64 + 4 * q);       \
    u1 = *(const float4*)(xlf + (size_t)r1_ * 64 + 4 * q);       \
    u2 = *(const float4*)(xlf + (size_t)r2_ * 64 + 4 * q);       \
    u3 = *(const float4*)(xlf + (size_t)r3_ * 64 + 4 * q);       \
  }
#define GACC4(u0, u1, u2, u3, a0, a1, a2, a3)                    \
  {                                                              \
    a0 += (u0.x + u1.x) + (u2.x + u3.x);                         \
    a1 += (u0.y + u1.y) + (u2.y + u3.y);                         \
    a2 += (u0.z + u1.z) + (u2.z + u3.z);                         \
    a3 += (u0.w + u1.w) + (u2.w + u3.w);                         \
  }
#define GLOAD2(sidx, i, u0, u1)                                  \
  {                                                              \
    int r0_ = __shfl(sidx, (i) + g, 64);                         \
    int r1_ = __shfl(sidx, (i) + 4 + g, 64);                     \
    u0 = *(const float4*)(xlf + (size_t)r0_ * 64 + 4 * q);       \
    u1 = *(const float4*)(xlf + (size_t)r1_ * 64 + 4 * q);       \
  }
#define GACC2(u0, u1, a0, a1, a2, a3)                            \
  {                                                              \
    a0 += u0.x + u1.x; a1 += u0.y + u1.y;                        \
    a2 += u0.z + u1.z; a3 += u0.w + u1.w;                        \
  }
#define GTAIL(sidx, ii, mm, a0, a1, a2, a3)                      \
  {                                                              \
    int e_ = (ii) + g;                                           \
    int r_ = __shfl(sidx, e_ & 63, 64);                          \
    float4 u_ = *(const float4*)(xlf + (size_t)r_ * 64 + 4 * q); \
    if (e_ < (mm)) { a0 += u_.x; a1 += u_.y; a2 += u_.z; a3 += u_.w; } \
  }

__global__ __launch_bounds__(256) void k_agg1(
    const int* __restrict__ cnt, const int* __restrict__ bucket,
    const float* __restrict__ xlf, const float* __restrict__ hrootf,
    float* __restrict__ hbuff, int Nn) {
  const int lane = threadIdx.x & 63;
  const int q = lane & 15;
  const int g = lane >> 4;
  const int nw = gridDim.x * (blockDim.x >> 6);
  const int stride = nw << 1;
  int nA = blockIdx.x * (blockDim.x >> 6) + (threadIdx.x >> 6);
  if (nA >= Nn) return;

  // pair-0 prologue: bucket rows loaded unconditionally (rows fully written),
  // lane<m mask + firewall applied after -> no cnt->bucket dependence.
  int nB = nA + nw;
  int nBc = min(nB, Nn - 1);
  int cA = cnt[nA];
  int cB = cnt[nBc];
  int rA0 = bucket[(size_t)nA * CAP + lane];
  int rB0 = bucket[(size_t)nBc * CAP + lane];
  int mA = cA < CAP ? cA : CAP;
  int mB = cB < CAP ? cB : CAP;
  int sidxA = (lane < mA && (unsigned)rA0 < (unsigned)Nn) ? rA0 : 0;
  int sidxB = (lane < mB && (unsigned)rB0 < (unsigned)Nn) ? rB0 : 0;

  while (true) {
    // next-pair prefetch: all independent loads, land during this pair's work
    const int nA1 = nA + stride;
    const int nA1c = min(nA1, Nn - 1);
    const int nB1c = min(nA1 + nw, Nn - 1);
    int cA1 = cnt[nA1c];
    int cB1 = cnt[nB1c];
    int rawA1 = bucket[(size_t)nA1c * CAP + lane];
    int rawB1 = bucket[(size_t)nB1c * CAP + lane];
    float4 huA = *(const float4*)(hrootf + (size_t)nA * 64 + 4 * q);
    float4 huB = *(const float4*)(hrootf + (size_t)nBc * 64 + 4 * q);

    float aA0 = 0.f, aA1 = 0.f, aA2 = 0.f, aA3 = 0.f;
    float aB0 = 0.f, aB1 = 0.f, aB2 = 0.f, aB3 = 0.f;
    int iA = 0, iB = 0;
    // dual 16-edge stages: 8 float4 gathers in flight
    while (iA + 16 <= mA && iB + 16 <= mB) {
      float4 A0, A1, A2, A3, B0, B1, B2, B3;
      GLOAD4(sidxA, iA, A0, A1, A2, A3);
      GLOAD4(sidxB, iB, B0, B1, B2, B3);
      GACC4(A0, A1, A2, A3, aA0, aA1, aA2, aA3);
      GACC4(B0, B1, B2, B3, aB0, aB1, aB2, aB3);
      iA += 16; iB += 16;
    }
    while (iA + 16 <= mA) {
      float4 A0, A1, A2, A3;
      GLOAD4(sidxA, iA, A0, A1, A2, A3);
      GACC4(A0, A1, A2, A3, aA0, aA1, aA2, aA3);
      iA += 16;
    }
    while (iB + 16 <= mB) {
      float4 B0, B1, B2, B3;
      GLOAD4(sidxB, iB, B0, B1, B2, B3);
      GACC4(B0, B1, B2, B3, aB0, aB1, aB2, aB3);
      iB += 16;
    }
    {
      const bool e8A = (iA + 8 <= mA), e8B = (iB + 8 <= mB);
      if (e8A && e8B) {
        float4 A0, A1, B0, B1;
        GLOAD2(sidxA, iA, A0, A1);
        GLOAD2(sidxB, iB, B0, B1);
        GACC2(A0, A1, aA0, aA1, aA2, aA3);
        GACC2(B0, B1, aB0, aB1, aB2, aB3);
        iA += 8; iB += 8;
      } else if (e8A) {
        float4 A0, A1;
        GLOAD2(sidxA, iA, A0, A1);
        GACC2(A0, A1, aA0, aA1, aA2, aA3);
        iA += 8;
      } else if (e8B) {
        float4 B0, B1;
        GLOAD2(sidxB, iB, B0, B1);
        GACC2(B0, B1, aB0, aB1, aB2, aB3);
        iB += 8;
      }
    }
    for (; iA < mA; iA += 4) GTAIL(sidxA, iA, mA, aA0, aA1, aA2, aA3);
    for (; iB < mB; iB += 4) GTAIL(sidxB, iB, mB, aB0, aB1, aB2, aB3);

    // merge the 4 edge-subgroups (both nodes)
    aA0 += __shfl_xor(aA0, 16, 64); aA0 += __shfl_xor(aA0, 32, 64);
    aA1 += __shfl_xor(aA1, 16, 64); aA1 += __shfl_xor(aA1, 32, 64);
    aA2 += __shfl_xor(aA2, 16, 64); aA2 += __shfl_xor(aA2, 32, 64);
    aA3 += __shfl_xor(aA3, 16, 64); aA3 += __shfl_xor(aA3, 32, 64);
    aB0 += __shfl_xor(aB0, 16, 64); aB0 += __shfl_xor(aB0, 32, 64);
    aB1 += __shfl_xor(aB1, 16, 64); aB1 += __shfl_xor(aB1, 32, 64);
    aB2 += __shfl_xor(aB2, 16, 64); aB2 += __shfl_xor(aB2, 32, 64);
    aB3 += __shfl_xor(aB3, 16, 64); aB3 += __shfl_xor(aB3, 32, 64);
    if (g == 0) {
      float invA = 1.f / (cA > 0 ? (float)cA : 1.f);
      float4 o;
      o.x = fmaxf(fmaf(aA0, invA, huA.x), 0.f);
      o.y = fmaxf(fmaf(aA1, invA, huA.y), 0.f);
      o.z = fmaxf(fmaf(aA2, invA, huA.z), 0.f);
      o.w = fmaxf(fmaf(aA3, invA, huA.w), 0.f);
      *(float4*)(hbuff + (size_t)nA * 64 + 4 * q) = o;
      if (nB < Nn) {
        float invB = 1.f / (cB > 0 ? (float)cB : 1.f);
        float4 p2;
        p2.x = fmaxf(fmaf(aB0, invB, huB.x), 0.f);
        p2.y = fmaxf(fmaf(aB1, invB, huB.y), 0.f);
        p2.z = fmaxf(fmaf(aB2, invB, huB.z), 0.f);
        p2.w = fmaxf(fmaf(aB3, invB, huB.w), 0.f);
        *(float4*)(hbuff + (size_t)nB * 64 + 4 * q) = p2;
      }
    }
    if (nA1 >= Nn) break;
    // rotate pair pipeline
    nA = nA1; nB = nA + nw; nBc = min(nB, Nn - 1);
    cA = cA1; cB = cB1;
    mA = cA < CAP ? cA : CAP;
    mB = cB < CAP ? cB : CAP;
    sidxA = (lane < mA && (unsigned)rawA1 < (unsigned)Nn) ? rawA1 : 0;
    sidxB = (lane < mB && (unsigned)rawB1 < (unsigned)Nn) ? rawB1 : 0;
  }
}

// ---------------- layer-2 GEMMs: hl = h@W2l, hr = h@W2r + b2 ; stride-8 rows ----------------
__global__ __launch_bounds__(128) void k_gemm2(
    const float* __restrict__ hbuf,
    const float* __restrict__ W2l, const float* __restrict__ W2r,
    const float* __restrict__ b2,
    float* __restrict__ hl, float* __restrict__ hr, int Nn) {
  __shared__ float tile[128 * 65];  // +1 pad: conflict-free column reads
  const int t = threadIdx.x;
  const int rowbase = blockIdx.x * 128;
  for (int idx = t; idx < 128 * 64; idx += 128) {
    int r = idx >> 6, k = idx & 63;
    int n = rowbase + r;
    tile[r * 65 + k] = (n < Nn) ? hbuf[(size_t)n * 64 + k] : 0.f;
  }
  __syncthreads();
  int n = rowbase + t;
  if (n >= Nn) return;
  float al[7] = {0, 0, 0, 0, 0, 0, 0};
  float ar[7] = {0, 0, 0, 0, 0, 0, 0};
  for (int k = 0; k < 64; ++k) {
    float hv = tile[t * 65 + k];
    #pragma unroll
    for (int c = 0; c < 7; ++c) {
      al[c] = fmaf(hv, W2l[k * 7 + c], al[c]);
      ar[c] = fmaf(hv, W2r[k * 7 + c], ar[c]);
    }
  }
  #pragma unroll
  for (int c = 0; c < 7; ++c) {
    hl[(size_t)n * 8 + c] = al[c];
    hr[(size_t)n * 8 + c] = ar[c] + b2[c];
  }
  hl[(size_t)n * 8 + 7] = 0.f;
  hr[(size_t)n * 8 + 7] = 0.f;
}

// ---------------- layer-2 aggregate + log_softmax; 8 nodes/wave, 8 lanes/node ----------------
__global__ __launch_bounds__(256) void k_out(
    const int* __restrict__ cnt, const int* __restrict__ bucket,
    const float* __restrict__ hl, const float* __restrict__ hr,
    float* __restrict__ out, int Nn) {
  const int lane = threadIdx.x & 63;
  const int c = lane & 7;
  const int sub = lane >> 3;
  const int gw = blockIdx.x * (blockDim.x >> 6) + (threadIdx.x >> 6);
  const int n = gw * 8 + sub;
  if (n >= Nn) return;
  int cn = cnt[n];
  int m = cn < CAP ? cn : CAP;
  const bool act = (c < 7);
  float acc = 0.f;
  for (int e0 = 0; e0 < m; e0 += 8) {
    int bv = (e0 + c < m) ? bucket[(size_t)n * CAP + e0 + c] : 0;
    #pragma unroll
    for (int cc = 0; cc < 8; ++cc) {
      if (e0 + cc < m) {
        int s = __shfl(bv, (lane & 56) + cc, 64);
        if ((unsigned)s >= (unsigned)Nn) s = 0;
        if (act) acc += hl[(size_t)s * 8 + c];
      }
    }
  }
  float dd = cn > 0 ? (float)cn : 1.f;
  float v = act ? (acc / dd + hr[(size_t)n * 8 + c]) : -INFINITY;
  float mx = v;
  mx = fmaxf(mx, __shfl_xor(mx, 1, 8));
  mx = fmaxf(mx, __shfl_xor(mx, 2, 8));
  mx = fmaxf(mx, __shfl_xor(mx, 4, 8));
  float ex = act ? expf(v - mx) : 0.f;
  float s2 = ex;
  s2 += __shfl_xor(s2, 1, 8);
  s2 += __shfl_xor(s2, 2, 8);
  s2 += __shfl_xor(s2, 4, 8);
  float res = v - mx - logf(s2);
  if (act) out[(size_t)n * 7 + c] = res;
}

static inline size_t alignup(size_t v) { return (v + 255) & ~(size_t)255; }

extern "C" void kernel_launch(void* const* d_in, const int* in_sizes, int n_in,
                              void* d_out, int out_size, void* d_ws, size_t ws_size,
                              hipStream_t stream) {
  const int N = in_sizes[0] / 128;
  const int E = in_sizes[1] / 2;
  const int NB = (N + BINSZ - 1) / BINSZ;   // 782 bins
  const int Np = NB * BINSZ;                // padded node count
  const int NCH = (E + CH - 1) / CH;        // 391 chunks
  const int nScan = (NB + 3) / 4;           // scanA head blocks

  const float* x   = (const float*)d_in[0];
  const int*   ei  = (const int*)d_in[1];
  const float* W1l = (const float*)d_in[2];
  const float* W1r = (const float*)d_in[3];
  const float* b1  = (const float*)d_in[4];
  const float* W2l = (const float*)d_in[5];
  const float* W2r = (const float*)d_in[6];
  const float* b2  = (const float*)d_in[7];
  float* out = (float*)d_out;

  // workspace carve (~117 MB)
  char* p = (char*)d_ws;
  int* hist    = (int*)p;            p += alignup((size_t)NB * NCH * 4);
  int* tot     = (int*)p;            p += alignup((size_t)NB * 4);
  int* binbase = (int*)p;            p += alignup((size_t)(NB + 1) * 4);
  int* cursor  = (int*)p;            p += alignup(4);
  unsigned int* part = (unsigned int*)p; p += alignup((size_t)E * 4);
  int* cnt    = (int*)p;             p += alignup((size_t)Np * 4);
  int* bucket = (int*)p;             p += alignup((size_t)Np * CAP * 4);
  unsigned short* wswz = (unsigned short*)p; p += alignup((size_t)16384 * 2);
  float* xl    = (float*)p;          p += alignup((size_t)N * 64 * 4);
  float* hroot = (float*)p;          p += alignup((size_t)N * 64 * 4);
  float* hbuf  = (float*)p;          p += alignup((size_t)N * 64 * 4);
  float* hl  = (float*)p;            p += alignup((size_t)N * 8 * 4);
  float* hr  = (float*)p;            p += alignup((size_t)N * 8 * 4);

  dim3 b256(256);
  // hist blocks [0,NCH) + wprep/cursor tail blocks [NCH, NCH+64)
  k_hist<<<dim3(NCH + 64), b256, 0, stream>>>(ei, hist, W1l, W1r, wswz, cursor, E, NB, NCH);
  // scanA head blocks [0,nScan) + gemm1 tail blocks
  k_scan_gemm<<<dim3(nScan + (N + 63) / 64), b256, 0, stream>>>(
      hist, tot, binbase, cursor, NB, NCH, nScan, x, wswz, b1, xl, hroot, N);
  k_scat<<<dim3(NCH), b256, 0, stream>>>(ei, hist, binbase, part, E, NB, NCH);
  k_bucketB<<<dim3(NB), b256, 0, stream>>>(binbase, tot, part, cnt, bucket);
  k_agg1<<<dim3(2048), b256, 0, stream>>>(cnt, bucket, xl, hroot, hbuf, N);
  k_gemm2<<<dim3((N + 127) / 128), dim3(128), 0, stream>>>(hbuf, W2l, W2r, b2, hl, hr, N);
  const int waves_out = (N + 7) / 8;
  k_out<<<dim3((waves_out + 3) / 4), b256, 0, stream>>>(cnt, bucket, hl, hr, out, N);
}

// Round 4
// 250.746 us; speedup vs baseline: 1.1350x; 1.1350x over previous
//
#include <hip/hip_runtime.h>
#include <cstdint>
#include <cstddef>

// GraphSAGE 2-layer fused pipeline, MI355X.
// Identity: segment_mean(x[src]) @ W == segment_mean((x@W)[src]) -> GEMM before gather.
// R23: R22's f32 experiment ISOLATED the tradeoff: f32 halved VALU busy
// (26.4us->15.2us) but doubled HBM fetch (89.6->200MB; L3 does NOT retain xl,
// HBM bytes track gather bytes at ~0.36x) -> memory-bound 64.7us @3.56TB/s.
// R23 takes the best of both: bf16 storage (gather bytes halved, FETCH ~90MB)
// + R22's latency machinery (dual-node interleave, unconditional bucket rows,
// next-pair prefetch) that demonstrated 3.5TB/s sustainable, + rcpf instead of
// 4 f32 divides. Memory floor ~105MB/3.5TB/s ~= 30us; VALU busy ~18us.

#define CAP 64
#define BINSZ 128        // nodes per bin (dst >> 7)
#define CH 4096          // edges per chunk block

typedef __attribute__((ext_vector_type(8))) short bf16x8v;
typedef __attribute__((ext_vector_type(4))) float f32x4v;

__device__ __forceinline__ float bf2f(unsigned short u) {
  return __uint_as_float(((unsigned int)u) << 16);
}
__device__ __forceinline__ unsigned short f2bf(float f) {
  unsigned int x = __float_as_uint(f);
  unsigned int r = (x + 0x7fffu + ((x >> 16) & 1u)) >> 16;  // RNE
  return (unsigned short)r;
}

// ---------------- pass 1: per-chunk histogram over dst bins + (tail blocks) W-swizzle ----------------
__global__ __launch_bounds__(256) void k_hist(const int* __restrict__ ei,
                                              int* __restrict__ hist,
                                              const float* __restrict__ W1l,
                                              const float* __restrict__ W1r,
                                              unsigned short* __restrict__ wswz,
                                              int* __restrict__ cursor,
                                              int E, int NB, int NCH) {
  const int t = threadIdx.x;
  if (blockIdx.x >= (unsigned)NCH) {
    if (blockIdx.x == (unsigned)NCH && t == 0) *cursor = 0;  // scanA base cursor
    // wprep tail: 64 blocks cover 16384 swizzled bf16 weights
    int idx = (blockIdx.x - NCH) * 256 + t;
    int j = idx & 7;
    int lane = (idx >> 3) & 63;
    int c = (idx >> 9) & 7;
    int t4 = idx >> 12;
    int kk = t4 * 32 + (lane >> 4) * 8 + j;
    int nn = c * 16 + (lane & 15);
    float v = (nn < 64) ? W1l[kk * 64 + nn] : W1r[kk * 64 + (nn - 64)];
    wswz[idx] = f2bf(v);
    return;
  }
  __shared__ int lcnt[1024];
  const int c = blockIdx.x;
  for (int i = t; i < NB; i += 256) lcnt[i] = 0;
  __syncthreads();
  const int base = c * CH;
  const int end = min(base + CH, E);
  for (int e = base + t; e < end; e += 256) {
    int d = ei[E + e];
    atomicAdd(&lcnt[d >> 7], 1);  // LDS int atomic (native, fast)
  }
  __syncthreads();
  for (int i = t; i < NB; i += 256) hist[(size_t)i * NCH + c] = lcnt[i];
}

// ---------------- merged: [head blocks] per-bin scan over chunks  |  [tail blocks] layer-1 GEMM ----------------
// scanA: 1 wave/bin exclusive scan of hist rows -> tot + atomic binbase.
// gemm1: [xl|hroot] = x @ [W1l|W1r] (+b1), bf16 outputs.
__global__ __launch_bounds__(256) void k_scan_gemm(
    int* __restrict__ hist, int* __restrict__ tot, int* __restrict__ binbase,
    int* __restrict__ cursor, int NB, int NCH, int nScan,
    const float* __restrict__ x, const unsigned short* __restrict__ wswz,
    const float* __restrict__ b1, unsigned short* __restrict__ xl,
    unsigned short* __restrict__ hroot, int Nn) {
  if (blockIdx.x < (unsigned)nScan) {
    const int lane = threadIdx.x & 63;
    const int bin = blockIdx.x * 4 + (threadIdx.x >> 6);
    if (bin >= NB) return;
    int* h = hist + (size_t)bin * NCH;
    int carry = 0;
    for (int base = 0; base < NCH; base += 64) {
      int i = base + lane;
      int v = (i < NCH) ? h[i] : 0;
      int incl = v;
      #pragma unroll
      for (int d = 1; d < 64; d <<= 1) {
        int t = __shfl_up(incl, d, 64);
        if (lane >= d) incl += t;
      }
      if (i < NCH) h[i] = carry + incl - v;  // exclusive prefix within bin
      carry += __shfl(incl, 63, 64);
    }
    if (lane == 0) {
      tot[bin] = carry;
      binbase[bin] = atomicAdd(cursor, carry);  // disjoint range, order-free
    }
    return;
  }
  // ---- gemm1 body ----
  __shared__ unsigned short Bsw[16384];  // 32 KB
  const int t = threadIdx.x;
  const int bid = blockIdx.x - nScan;
  {
    const uint4* src = (const uint4*)wswz;
    uint4* dst = (uint4*)Bsw;
    #pragma unroll
    for (int i = 0; i < 8; ++i) dst[t + i * 256] = src[t + i * 256];
  }
  __syncthreads();

  const int lane = t & 63;
  const int wid = t >> 6;
  const int quad = lane >> 4;
  const int m = lane & 15;
  const int rowA = bid * 64 + wid * 16 + m;
  const float* xrow = x + (size_t)min(rowA, Nn - 1) * 128;

  f32x4v acc[8];
  #pragma unroll
  for (int c = 0; c < 8; ++c) acc[c] = (f32x4v){0.f, 0.f, 0.f, 0.f};

  #pragma unroll
  for (int t4 = 0; t4 < 4; ++t4) {
    const int koff = t4 * 32 + quad * 8;
    float4 a0 = *(const float4*)(xrow + koff);
    float4 a1 = *(const float4*)(xrow + koff + 4);
    bf16x8v af;
    af[0] = (short)f2bf(a0.x); af[1] = (short)f2bf(a0.y);
    af[2] = (short)f2bf(a0.z); af[3] = (short)f2bf(a0.w);
    af[4] = (short)f2bf(a1.x); af[5] = (short)f2bf(a1.y);
    af[6] = (short)f2bf(a1.z); af[7] = (short)f2bf(a1.w);
    #pragma unroll
    for (int c = 0; c < 8; ++c) {
      const bf16x8v bf_ = *(const bf16x8v*)&Bsw[(((t4 * 8 + c) * 64 + lane)) << 3];
      acc[c] = __builtin_amdgcn_mfma_f32_16x16x32_bf16(af, bf_, acc[c], 0, 0, 0);
    }
  }

  const int rbase = bid * 64 + wid * 16 + quad * 4;
  #pragma unroll
  for (int c = 0; c < 8; ++c) {
    const int col = c * 16 + m;
    #pragma unroll
    for (int i = 0; i < 4; ++i) {
      const int r = rbase + i;
      if (r < Nn) {
        if (c < 4) xl[(size_t)r * 64 + col] = f2bf(acc[c][i]);
        else       hroot[(size_t)r * 64 + (col - 64)] = f2bf(acc[c][i] + b1[col - 64]);
      }
    }
  }
}

// ---------------- pass 3: scatter edges to bin-sorted array (LDS cursors only) ----------------
__global__ __launch_bounds__(256) void k_scat(const int* __restrict__ ei,
                                              const int* __restrict__ hist,
                                              const int* __restrict__ binbase,
                                              unsigned int* __restrict__ part,
                                              int E, int NB, int NCH) {
  __shared__ int lcur[1024];
  const int c = blockIdx.x, t = threadIdx.x;
  for (int i = t; i < NB; i += 256)
    lcur[i] = hist[(size_t)i * NCH + c] + binbase[i];
  __syncthreads();
  const int base = c * CH;
  const int end = min(base + CH, E);
  for (int e = base + t; e < end; e += 256) {
    int s = ei[e];        // src < 2^17
    int d = ei[E + e];    // dst
    int bin = d >> 7;
    int pos = atomicAdd(&lcur[bin], 1);  // LDS int atomic; positions exact
    part[pos] = (unsigned)s | ((unsigned)(d & 127) << 17);
  }
}

// ---------------- pass 4: per-bin bucket build in LDS, coalesced writeout ----------------
__global__ __launch_bounds__(256) void k_bucketB(const int* __restrict__ binbase,
                                                 const int* __restrict__ tot,
                                                 const unsigned int* __restrict__ part,
                                                 int* __restrict__ cnt,
                                                 int* __restrict__ bucket) {
  __shared__ int lbkt[BINSZ * CAP];  // 32 KB
  __shared__ int ldeg[BINSZ];
  const int b = blockIdx.x, t = threadIdx.x;
  if (t < BINSZ) ldeg[t] = 0;
  __syncthreads();
  const int e0 = binbase[b], e1 = e0 + tot[b];
  for (int i = e0 + t; i < e1; i += 256) {
    unsigned rec = part[i];
    int loc = rec >> 17;
    int p = atomicAdd(&ldeg[loc], 1);
    if (p < CAP) lbkt[loc * CAP + p] = (int)(rec & 0x1FFFFu);
  }
  __syncthreads();
  if (t < BINSZ) cnt[b * BINSZ + t] = ldeg[t];
  const int4* s4 = (const int4*)lbkt;
  int4* d4 = (int4*)(bucket + (size_t)b * BINSZ * CAP);
  #pragma unroll 2
  for (int i = t; i < BINSZ * CAP / 4; i += 256) d4[i] = s4[i];
}

// ---------------- layer-1 aggregate: h = relu(mean_nb(xl) + hroot), bf16 gather ----------------
// Wave per node-pair (A = n, B = n + nw), outer stride 2*nw. lane q=lane&15
// covers uint2 = bf16 cols {4q..4q+3}; g=lane>>4 picks edge subgroup.
// bf16 rows (128B) halve HBM fetch vs f32 (R22 measured 200MB->regression);
// dual-node + unconditional bucket rows keep R22's 3.5TB/s latency posture.
#define BLOAD4(sidx, i, u0, u1, u2, u3)                        \
  {                                                            \
    int r0_ = __shfl(sidx, (i) + g, 64);                       \
    int r1_ = __shfl(sidx, (i) + 4 + g, 64);                   \
    int r2_ = __shfl(sidx, (i) + 8 + g, 64);                   \
    int r3_ = __shfl(sidx, (i) + 12 + g, 64);                  \
    u0 = *(const uint2*)(xl32 + r0_ * 32 + qo);                \
    u1 = *(const uint2*)(xl32 + r1_ * 32 + qo);                \
    u2 = *(const uint2*)(xl32 + r2_ * 32 + qo);                \
    u3 = *(const uint2*)(xl32 + r3_ * 32 + qo);                \
  }
#define BACC4(u0, u1, u2, u3, a0, a1, a2, a3)                                        \
  {                                                                                  \
    a0 += (__uint_as_float(u0.x << 16) + __uint_as_float(u1.x << 16))                \
        + (__uint_as_float(u2.x << 16) + __uint_as_float(u3.x << 16));               \
    a1 += (__uint_as_float(u0.x & 0xFFFF0000u) + __uint_as_float(u1.x & 0xFFFF0000u))\
        + (__uint_as_float(u2.x & 0xFFFF0000u) + __uint_as_float(u3.x & 0xFFFF0000u));\
    a2 += (__uint_as_float(u0.y << 16) + __uint_as_float(u1.y << 16))                \
        + (__uint_as_float(u2.y << 16) + __uint_as_float(u3.y << 16));               \
    a3 += (__uint_as_float(u0.y & 0xFFFF0000u) + __uint_as_float(u1.y & 0xFFFF0000u))\
        + (__uint_as_float(u2.y & 0xFFFF0000u) + __uint_as_float(u3.y & 0xFFFF0000u));\
  }
#define BLOAD2(sidx, i, u0, u1)                                \
  {                                                            \
    int r0_ = __shfl(sidx, (i) + g, 64);                       \
    int r1_ = __shfl(sidx, (i) + 4 + g, 64);                   \
    u0 = *(const uint2*)(xl32 + r0_ * 32 + qo);                \
    u1 = *(const uint2*)(xl32 + r1_ * 32 + qo);                \
  }
#define BACC2(u0, u1, a0, a1, a2, a3)                                           \
  {                                                                             \
    a0 += __uint_as_float(u0.x << 16) + __uint_as_float(u1.x << 16);            \
    a1 += __uint_as_float(u0.x & 0xFFFF0000u) + __uint_as_float(u1.x & 0xFFFF0000u);\
    a2 += __uint_as_float(u0.y << 16) + __uint_as_float(u1.y << 16);            \
    a3 += __uint_as_float(u0.y & 0xFFFF0000u) + __uint_as_float(u1.y & 0xFFFF0000u);\
  }
#define BTAIL(sidx, ii, mm, a0, a1, a2, a3)                    \
  {                                                            \
    int e_ = (ii) + g;                                         \
    int r_ = __shfl(sidx, e_ & 63, 64);                        \
    uint2 u_ = *(const uint2*)(xl32 + r_ * 32 + qo);           \
    if (e_ < (mm)) {                                           \
      a0 += __uint_as_float(u_.x << 16);                       \
      a1 += __uint_as_float(u_.x & 0xFFFF0000u);               \
      a2 += __uint_as_float(u_.y << 16);                       \
      a3 += __uint_as_float(u_.y & 0xFFFF0000u);               \
    }                                                          \
  }

__global__ __launch_bounds__(256) void k_agg1(
    const int* __restrict__ cnt, const int* __restrict__ bucket,
    const unsigned int* __restrict__ xl32, const unsigned int* __restrict__ hroot32,
    unsigned int* __restrict__ hbuf32, int Nn) {
  const int lane = threadIdx.x & 63;
  const int q = lane & 15;
  const int qo = 2 * q;            // uint offset within 32-uint row
  const int g = lane >> 4;
  const int nw = gridDim.x * (blockDim.x >> 6);
  const int stride = nw << 1;
  int nA = blockIdx.x * (blockDim.x >> 6) + (threadIdx.x >> 6);
  if (nA >= Nn) return;

  // pair-0 prologue: bucket rows loaded unconditionally (rows fully written
  // by k_bucketB); lane<m mask + firewall applied after the load.
  int nB = nA + nw;
  int nBc = min(nB, Nn - 1);
  int cA = cnt[nA];
  int cB = cnt[nBc];
  int rA0 = bucket[(size_t)nA * CAP + lane];
  int rB0 = bucket[(size_t)nBc * CAP + lane];
  int mA = cA < CAP ? cA : CAP;
  int mB = cB < CAP ? cB : CAP;
  int sidxA = (lane < mA && (unsigned)rA0 < (unsigned)Nn) ? rA0 : 0;
  int sidxB = (lane < mB && (unsigned)rB0 < (unsigned)Nn) ? rB0 : 0;

  while (true) {
    // next-pair prefetch: independent loads land during this pair's gathers
    const int nA1 = nA + stride;
    const int nA1c = min(nA1, Nn - 1);
    const int nB1c = min(nA1 + nw, Nn - 1);
    int cA1 = cnt[nA1c];
    int cB1 = cnt[nB1c];
    int rawA1 = bucket[(size_t)nA1c * CAP + lane];
    int rawB1 = bucket[(size_t)nB1c * CAP + lane];
    uint2 huA = *(const uint2*)(hroot32 + (unsigned)nA * 32 + qo);
    uint2 huB = *(const uint2*)(hroot32 + (unsigned)nBc * 32 + qo);

    float aA0 = 0.f, aA1 = 0.f, aA2 = 0.f, aA3 = 0.f;
    float aB0 = 0.f, aB1 = 0.f, aB2 = 0.f, aB3 = 0.f;
    int iA = 0, iB = 0;
    // dual 16-edge stages: 8 gathers in flight
    while (iA + 16 <= mA && iB + 16 <= mB) {
      uint2 A0, A1, A2, A3, B0, B1, B2, B3;
      BLOAD4(sidxA, iA, A0, A1, A2, A3);
      BLOAD4(sidxB, iB, B0, B1, B2, B3);
      BACC4(A0, A1, A2, A3, aA0, aA1, aA2, aA3);
      BACC4(B0, B1, B2, B3, aB0, aB1, aB2, aB3);
      iA += 16; iB += 16;
    }
    while (iA + 16 <= mA) {
      uint2 A0, A1, A2, A3;
      BLOAD4(sidxA, iA, A0, A1, A2, A3);
      BACC4(A0, A1, A2, A3, aA0, aA1, aA2, aA3);
      iA += 16;
    }
    while (iB + 16 <= mB) {
      uint2 B0, B1, B2, B3;
      BLOAD4(sidxB, iB, B0, B1, B2, B3);
      BACC4(B0, B1, B2, B3, aB0, aB1, aB2, aB3);
      iB += 16;
    }
    {
      const bool e8A = (iA + 8 <= mA), e8B = (iB + 8 <= mB);
      if (e8A && e8B) {
        uint2 A0, A1, B0, B1;
        BLOAD2(sidxA, iA, A0, A1);
        BLOAD2(sidxB, iB, B0, B1);
        BACC2(A0, A1, aA0, aA1, aA2, aA3);
        BACC2(B0, B1, aB0, aB1, aB2, aB3);
        iA += 8; iB += 8;
      } else if (e8A) {
        uint2 A0, A1;
        BLOAD2(sidxA, iA, A0, A1);
        BACC2(A0, A1, aA0, aA1, aA2, aA3);
        iA += 8;
      } else if (e8B) {
        uint2 B0, B1;
        BLOAD2(sidxB, iB, B0, B1);
        BACC2(B0, B1, aB0, aB1, aB2, aB3);
        iB += 8;
      }
    }
    for (; iA < mA; iA += 4) BTAIL(sidxA, iA, mA, aA0, aA1, aA2, aA3);
    for (; iB < mB; iB += 4) BTAIL(sidxB, iB, mB, aB0, aB1, aB2, aB3);

    // merge the 4 edge-subgroups (both nodes)
    aA0 += __shfl_xor(aA0, 16, 64); aA0 += __shfl_xor(aA0, 32, 64);
    aA1 += __shfl_xor(aA1, 16, 64); aA1 += __shfl_xor(aA1, 32, 64);
    aA2 += __shfl_xor(aA2, 16, 64); aA2 += __shfl_xor(aA2, 32, 64);
    aA3 += __shfl_xor(aA3, 16, 64); aA3 += __shfl_xor(aA3, 32, 64);
    aB0 += __shfl_xor(aB0, 16, 64); aB0 += __shfl_xor(aB0, 32, 64);
    aB1 += __shfl_xor(aB1, 16, 64); aB1 += __shfl_xor(aB1, 32, 64);
    aB2 += __shfl_xor(aB2, 16, 64); aB2 += __shfl_xor(aB2, 32, 64);
    aB3 += __shfl_xor(aB3, 16, 64); aB3 += __shfl_xor(aB3, 32, 64);
    if (g == 0) {
      float invA = __builtin_amdgcn_rcpf(cA > 0 ? (float)cA : 1.f);
      float h0 = fmaxf(fmaf(aA0, invA, __uint_as_float(huA.x << 16)), 0.f);
      float h1 = fmaxf(fmaf(aA1, invA, __uint_as_float(huA.x & 0xFFFF0000u)), 0.f);
      float h2 = fmaxf(fmaf(aA2, invA, __uint_as_float(huA.y << 16)), 0.f);
      float h3 = fmaxf(fmaf(aA3, invA, __uint_as_float(huA.y & 0xFFFF0000u)), 0.f);
      uint2 o;
      o.x = (unsigned)f2bf(h0) | ((unsigned)f2bf(h1) << 16);
      o.y = (unsigned)f2bf(h2) | ((unsigned)f2bf(h3) << 16);
      *(uint2*)(hbuf32 + (unsigned)nA * 32 + qo) = o;
      if (nB < Nn) {
        float invB = __builtin_amdgcn_rcpf(cB > 0 ? (float)cB : 1.f);
        float g0 = fmaxf(fmaf(aB0, invB, __uint_as_float(huB.x << 16)), 0.f);
        float g1 = fmaxf(fmaf(aB1, invB, __uint_as_float(huB.x & 0xFFFF0000u)), 0.f);
        float g2 = fmaxf(fmaf(aB2, invB, __uint_as_float(huB.y << 16)), 0.f);
        float g3 = fmaxf(fmaf(aB3, invB, __uint_as_float(huB.y & 0xFFFF0000u)), 0.f);
        uint2 p2;
        p2.x = (unsigned)f2bf(g0) | ((unsigned)f2bf(g1) << 16);
        p2.y = (unsigned)f2bf(g2) | ((unsigned)f2bf(g3) << 16);
        *(uint2*)(hbuf32 + (unsigned)nB * 32 + qo) = p2;
      }
    }
    if (nA1 >= Nn) break;
    // rotate pair pipeline
    nA = nA1; nB = nA + nw; nBc = min(nB, Nn - 1);
    cA = cA1; cB = cB1;
    mA = cA < CAP ? cA : CAP;
    mB = cB < CAP ? cB : CAP;
    sidxA = (lane < mA && (unsigned)rawA1 < (unsigned)Nn) ? rawA1 : 0;
    sidxB = (lane < mB && (unsigned)rawB1 < (unsigned)Nn) ? rawB1 : 0;
  }
}

// ---------------- layer-2 GEMMs: hl = h@W2l, hr = h@W2r + b2 ; stride-8 rows ----------------
__global__ __launch_bounds__(128) void k_gemm2(
    const unsigned short* __restrict__ hbuf,
    const float* __restrict__ W2l, const float* __restrict__ W2r,
    const float* __restrict__ b2,
    float* __restrict__ hl, float* __restrict__ hr, int Nn) {
  __shared__ float tile[128 * 65];  // +1 pad: conflict-free column reads
  const int t = threadIdx.x;
  const int rowbase = blockIdx.x * 128;
  for (int idx = t; idx < 128 * 64; idx += 128) {
    int r = idx >> 6, k = idx & 63;
    int n = rowbase + r;
    tile[r * 65 + k] = (n < Nn) ? bf2f(hbuf[(size_t)n * 64 + k]) : 0.f;
  }
  __syncthreads();
  int n = rowbase + t;
  if (n >= Nn) return;
  float al[7] = {0, 0, 0, 0, 0, 0, 0};
  float ar[7] = {0, 0, 0, 0, 0, 0, 0};
  for (int k = 0; k < 64; ++k) {
    float hv = tile[t * 65 + k];
    #pragma unroll
    for (int c = 0; c < 7; ++c) {
      al[c] = fmaf(hv, W2l[k * 7 + c], al[c]);
      ar[c] = fmaf(hv, W2r[k * 7 + c], ar[c]);
    }
  }
  #pragma unroll
  for (int c = 0; c < 7; ++c) {
    hl[(size_t)n * 8 + c] = al[c];
    hr[(size_t)n * 8 + c] = ar[c] + b2[c];
  }
  hl[(size_t)n * 8 + 7] = 0.f;
  hr[(size_t)n * 8 + 7] = 0.f;
}

// ---------------- layer-2 aggregate + log_softmax; 8 nodes/wave, 8 lanes/node ----------------
__global__ __launch_bounds__(256) void k_out(
    const int* __restrict__ cnt, const int* __restrict__ bucket,
    const float* __restrict__ hl, const float* __restrict__ hr,
    float* __restrict__ out, int Nn) {
  const int lane = threadIdx.x & 63;
  const int c = lane & 7;
  const int sub = lane >> 3;
  const int gw = blockIdx.x * (blockDim.x >> 6) + (threadIdx.x >> 6);
  const int n = gw * 8 + sub;
  if (n >= Nn) return;
  int cn = cnt[n];
  int m = cn < CAP ? cn : CAP;
  const bool act = (c < 7);
  float acc = 0.f;
  for (int e0 = 0; e0 < m; e0 += 8) {
    int bv = (e0 + c < m) ? bucket[(size_t)n * CAP + e0 + c] : 0;
    #pragma unroll
    for (int cc = 0; cc < 8; ++cc) {
      if (e0 + cc < m) {
        int s = __shfl(bv, (lane & 56) + cc, 64);
        if ((unsigned)s >= (unsigned)Nn) s = 0;
        if (act) acc += hl[(size_t)s * 8 + c];
      }
    }
  }
  float dd = cn > 0 ? (float)cn : 1.f;
  float v = act ? (acc / dd + hr[(size_t)n * 8 + c]) : -INFINITY;
  float mx = v;
  mx = fmaxf(mx, __shfl_xor(mx, 1, 8));
  mx = fmaxf(mx, __shfl_xor(mx, 2, 8));
  mx = fmaxf(mx, __shfl_xor(mx, 4, 8));
  float ex = act ? expf(v - mx) : 0.f;
  float s2 = ex;
  s2 += __shfl_xor(s2, 1, 8);
  s2 += __shfl_xor(s2, 2, 8);
  s2 += __shfl_xor(s2, 4, 8);
  float res = v - mx - logf(s2);
  if (act) out[(size_t)n * 7 + c] = res;
}

static inline size_t alignup(size_t v) { return (v + 255) & ~(size_t)255; }

extern "C" void kernel_launch(void* const* d_in, const int* in_sizes, int n_in,
                              void* d_out, int out_size, void* d_ws, size_t ws_size,
                              hipStream_t stream) {
  const int N = in_sizes[0] / 128;
  const int E = in_sizes[1] / 2;
  const int NB = (N + BINSZ - 1) / BINSZ;   // 782 bins
  const int Np = NB * BINSZ;                // padded node count
  const int NCH = (E + CH - 1) / CH;        // 391 chunks
  const int nScan = (NB + 3) / 4;           // scanA head blocks

  const float* x   = (const float*)d_in[0];
  const int*   ei  = (const int*)d_in[1];
  const float* W1l = (const float*)d_in[2];
  const float* W1r = (const float*)d_in[3];
  const float* b1  = (const float*)d_in[4];
  const float* W2l = (const float*)d_in[5];
  const float* W2r = (const float*)d_in[6];
  const float* b2  = (const float*)d_in[7];
  float* out = (float*)d_out;

  // workspace carve (~82 MB)
  char* p = (char*)d_ws;
  int* hist    = (int*)p;            p += alignup((size_t)NB * NCH * 4);
  int* tot     = (int*)p;            p += alignup((size_t)NB * 4);
  int* binbase = (int*)p;            p += alignup((size_t)(NB + 1) * 4);
  int* cursor  = (int*)p;            p += alignup(4);
  unsigned int* part = (unsigned int*)p; p += alignup((size_t)E * 4);
  int* cnt    = (int*)p;             p += alignup((size_t)Np * 4);
  int* bucket = (int*)p;             p += alignup((size_t)Np * CAP * 4);
  unsigned short* wswz = (unsigned short*)p; p += alignup((size_t)16384 * 2);
  unsigned short* xl    = (unsigned short*)p; p += alignup((size_t)N * 64 * 2);
  unsigned short* hroot = (unsigned short*)p; p += alignup((size_t)N * 64 * 2);
  unsigned short* hbuf  = (unsigned short*)p; p += alignup((size_t)N * 64 * 2);
  float* hl  = (float*)p;            p += alignup((size_t)N * 8 * 4);
  float* hr  = (float*)p;            p += alignup((size_t)N * 8 * 4);

  dim3 b256(256);
  // hist blocks [0,NCH) + wprep/cursor tail blocks [NCH, NCH+64)
  k_hist<<<dim3(NCH + 64), b256, 0, stream>>>(ei, hist, W1l, W1r, wswz, cursor, E, NB, NCH);
  // scanA head blocks [0,nScan) + gemm1 tail blocks
  k_scan_gemm<<<dim3(nScan + (N + 63) / 64), b256, 0, stream>>>(
      hist, tot, binbase, cursor, NB, NCH, nScan, x, wswz, b1, xl, hroot, N);
  k_scat<<<dim3(NCH), b256, 0, stream>>>(ei, hist, binbase, part, E, NB, NCH);
  k_bucketB<<<dim3(NB), b256, 0, stream>>>(binbase, tot, part, cnt, bucket);
  k_agg1<<<dim3(2048), b256, 0, stream>>>(cnt, bucket,
      (const unsigned int*)xl, (const unsigned int*)hroot, (unsigned int*)hbuf, N);
  k_gemm2<<<dim3((N + 127) / 128), dim3(128), 0, stream>>>(hbuf, W2l, W2r, b2, hl, hr, N);
  const int waves_out = (N + 7) / 8;
  k_out<<<dim3((waves_out + 3) / 4), b256, 0, stream>>>(cnt, bucket, hl, hr, out, N);
}